// Round 5
// baseline (1054.489 us; speedup 1.0000x reference)
//
#include <hip/hip_runtime.h>
#include <hip/hip_bf16.h>
#include <math.h>

// Problem dims (fixed by reference)
#define BN 1536          // B*N = 2*768
#define NN 768
#define SCALE 0.17677669529663687f  // 1/sqrt(32)
#define NROWS (BN * NN)  // total edge rows = 1179648
#define TROWS 16         // rows per k_bias tile (8 KB)
#define WAVES_TOTAL 1024 // 256 blocks * 4 waves
#define ROWS_PER_WAVE (NROWS / WAVES_TOTAL)   // 1152
#define NTILES (ROWS_PER_WAVE / TROWS)        // 72

// MEASUREMENT ROUND: k_bias and k_attn3 take a runtime `reps` and redo the
// identical (idempotent) work reps times, so their dispatch durations exceed
// the harness's ~370us fillBuffer dispatches and surface in the top-5 rocprof
// table with full counters. Work per rep is bit-identical to round 4.

// select a[idx] from a compile-time-unrolled register array (idx per-lane runtime)
__device__ __forceinline__ float sel8(const float* a, int idx) {
    float r = a[0];
#pragma unroll
    for (int t = 1; t < 8; ++t) r = (idx == t) ? a[t] : r;
    return r;
}

// async global->LDS, 16B per lane; LDS dest = wave-uniform base + lane*16
__device__ __forceinline__ void gl_lds16(const float* g, float* l) {
    __builtin_amdgcn_global_load_lds(
        (const __attribute__((address_space(1))) void*)g,
        (__attribute__((address_space(3))) void*)l, 16, 0, 0);
}

// ---------------------------------------------------------------------------
// K1: x = LN(node); q = SCALE*(x@Wq); k = x@Wk; v = x@Wv; g = sigmoid(x@Wg+bg)
// ---------------------------------------------------------------------------
__global__ __launch_bounds__(256) void k_lnproj(
    const float* __restrict__ node, const float* __restrict__ lnw,
    const float* __restrict__ lnb, const float* __restrict__ Wq,
    const float* __restrict__ Wk, const float* __restrict__ Wv,
    const float* __restrict__ Wg, const float* __restrict__ bg,
    float* __restrict__ q, float* __restrict__ k,
    float* __restrict__ v, float* __restrict__ g)
{
    __shared__ float xs[8][256];
    const int tid = threadIdx.x;
    const int wave = tid >> 6, lane = tid & 63;
    const int row0 = blockIdx.x * 8;

#pragma unroll
    for (int rr = 0; rr < 2; ++rr) {
        const int r = wave * 2 + rr;
        float4 xv = ((const float4*)node)[(size_t)(row0 + r) * 64 + lane];
        float s1 = xv.x + xv.y + xv.z + xv.w;
        float s2 = fmaf(xv.x, xv.x, fmaf(xv.y, xv.y, fmaf(xv.z, xv.z, xv.w * xv.w)));
#pragma unroll
        for (int off = 32; off > 0; off >>= 1) {
            s1 += __shfl_xor(s1, off);
            s2 += __shfl_xor(s2, off);
        }
        const float mu = s1 * (1.f / 256.f);
        const float rstd = rsqrtf(s2 * (1.f / 256.f) - mu * mu + 1e-5f);
        float4 w4 = ((const float4*)lnw)[lane];
        float4 b4 = ((const float4*)lnb)[lane];
        xs[r][lane * 4 + 0] = (xv.x - mu) * rstd * w4.x + b4.x;
        xs[r][lane * 4 + 1] = (xv.y - mu) * rstd * w4.y + b4.y;
        xs[r][lane * 4 + 2] = (xv.z - mu) * rstd * w4.z + b4.z;
        xs[r][lane * 4 + 3] = (xv.w - mu) * rstd * w4.w + b4.w;
    }
    __syncthreads();

    float aq[8] = {}, ak[8] = {}, av[8] = {}, ag[8] = {};
    for (int e4 = 0; e4 < 64; ++e4) {
        const int e = e4 * 4;
        float wq_[4], wk_[4], wv_[4], wg_[4];
#pragma unroll
        for (int t = 0; t < 4; ++t) {
            wq_[t] = Wq[(e + t) * 256 + tid];
            wk_[t] = Wk[(e + t) * 256 + tid];
            wv_[t] = Wv[(e + t) * 256 + tid];
            wg_[t] = Wg[(e + t) * 256 + tid];
        }
#pragma unroll
        for (int r = 0; r < 8; ++r) {
            float4 xr = *(const float4*)&xs[r][e];
            aq[r] = fmaf(xr.x, wq_[0], fmaf(xr.y, wq_[1], fmaf(xr.z, wq_[2], fmaf(xr.w, wq_[3], aq[r]))));
            ak[r] = fmaf(xr.x, wk_[0], fmaf(xr.y, wk_[1], fmaf(xr.z, wk_[2], fmaf(xr.w, wk_[3], ak[r]))));
            av[r] = fmaf(xr.x, wv_[0], fmaf(xr.y, wv_[1], fmaf(xr.z, wv_[2], fmaf(xr.w, wv_[3], av[r]))));
            ag[r] = fmaf(xr.x, wg_[0], fmaf(xr.y, wg_[1], fmaf(xr.z, wg_[2], fmaf(xr.w, wg_[3], ag[r]))));
        }
    }
    const float bgv = bg[tid];
#pragma unroll
    for (int r = 0; r < 8; ++r) {
        const size_t o = (size_t)(row0 + r) * 256 + tid;
        q[o] = aq[r] * SCALE;
        k[o] = ak[r];
        v[o] = av[r];
        g[o] = 1.f / (1.f + __expf(-(ag[r] + bgv)));
    }
}

// ---------------------------------------------------------------------------
// K2a: bias[r][h] = LN(edge_row r) @ Wb  (round-4 body, wrapped in reps)
// ---------------------------------------------------------------------------
__global__ __launch_bounds__(256) void k_bias(
    const float* __restrict__ edge, const float* __restrict__ lnw,
    const float* __restrict__ lnb, const float* __restrict__ Wb,
    float* __restrict__ bias, int reps)
{
    __shared__ float lds[4][2][TROWS * 128];   // 64 KB total
    const int tid = threadIdx.x;
    const int wave = tid >> 6, lane = tid & 63;
    const int g = lane & 7;

    float wbf[16][8];
    float c1p[8], c0p[8];
#pragma unroll
    for (int hh = 0; hh < 8; ++hh) { c1p[hh] = 0.f; c0p[hh] = 0.f; }
#pragma unroll
    for (int cc = 0; cc < 16; ++cc) {
        const int c = g * 16 + cc;
        const float w = lnw[c], bb = lnb[c];
        const float4 wa = ((const float4*)Wb)[c * 2];
        const float4 wc = ((const float4*)Wb)[c * 2 + 1];
        wbf[cc][0] = w * wa.x; wbf[cc][1] = w * wa.y;
        wbf[cc][2] = w * wa.z; wbf[cc][3] = w * wa.w;
        wbf[cc][4] = w * wc.x; wbf[cc][5] = w * wc.y;
        wbf[cc][6] = w * wc.z; wbf[cc][7] = w * wc.w;
        c0p[0] = fmaf(bb, wa.x, c0p[0]); c0p[1] = fmaf(bb, wa.y, c0p[1]);
        c0p[2] = fmaf(bb, wa.z, c0p[2]); c0p[3] = fmaf(bb, wa.w, c0p[3]);
        c0p[4] = fmaf(bb, wc.x, c0p[4]); c0p[5] = fmaf(bb, wc.y, c0p[5]);
        c0p[6] = fmaf(bb, wc.z, c0p[6]); c0p[7] = fmaf(bb, wc.w, c0p[7]);
#pragma unroll
        for (int hh = 0; hh < 8; ++hh) c1p[hh] += wbf[cc][hh];
    }
#pragma unroll
    for (int off = 1; off < 8; off <<= 1) {
#pragma unroll
        for (int hh = 0; hh < 8; ++hh) {
            c1p[hh] += __shfl_xor(c1p[hh], off);
            c0p[hh] += __shfl_xor(c0p[hh], off);
        }
    }
    const float c1s = sel8(c1p, g);
    const float c0s = sel8(c0p, g);

    const int wid = blockIdx.x * 4 + wave;                // 0..1023
    const size_t row0 = (size_t)wid * ROWS_PER_WAVE;      // 1152 rows/wave
    float* buf0 = &lds[wave][0][0];
    float* buf1 = &lds[wave][1][0];

    const int lh = lane >> 5;        // 0/1
    const int u = lane & 31;
#define PREFETCH(GBASE, BUF)                                              \
    {                                                                     \
        const float* _gb = (GBASE);                                       \
        float* _lb = (BUF);                                               \
        _Pragma("unroll")                                                 \
        for (int _i = 0; _i < 8; ++_i) {                                  \
            const int _r = 2 * _i + lh;                                   \
            gl_lds16(_gb + _r * 128 + ((u ^ (_r & 7)) << 2),              \
                     _lb + _i * 256);                                     \
        }                                                                 \
    }

    const int rgrp = lane >> 3;      // 0..7: row within 8-row pass

    for (int rep = 0; rep < reps; ++rep) {
        PREFETCH(edge + row0 * 128, buf0);
        float* cur = buf0;
        float* nxt = buf1;

        for (int t = 0; t < NTILES; ++t) {
            if (t + 1 < NTILES) {
                PREFETCH(edge + (row0 + (size_t)(t + 1) * TROWS) * 128, nxt);
                asm volatile("s_waitcnt vmcnt(8)" ::: "memory");
            } else {
                asm volatile("s_waitcnt vmcnt(0)" ::: "memory");
            }
            __builtin_amdgcn_sched_barrier(0);

#pragma unroll
            for (int p = 0; p < 2; ++p) {
                const int rl = p * 8 + rgrp;
                const int sw = rl & 7;
                const float* rowb = cur + rl * 128;
                const float4 x0 = *(const float4*)(rowb + (((g * 4 + 0) ^ sw) << 2));
                const float4 x1 = *(const float4*)(rowb + (((g * 4 + 1) ^ sw) << 2));
                const float4 x2 = *(const float4*)(rowb + (((g * 4 + 2) ^ sw) << 2));
                const float4 x3 = *(const float4*)(rowb + (((g * 4 + 3) ^ sw) << 2));

                float s1 = ((x0.x + x0.y) + (x0.z + x0.w)) + ((x1.x + x1.y) + (x1.z + x1.w))
                         + ((x2.x + x2.y) + (x2.z + x2.w)) + ((x3.x + x3.y) + (x3.z + x3.w));
                float s2 = fmaf(x0.x, x0.x, fmaf(x0.y, x0.y, fmaf(x0.z, x0.z, x0.w * x0.w)));
                s2 = fmaf(x1.x, x1.x, fmaf(x1.y, x1.y, fmaf(x1.z, x1.z, fmaf(x1.w, x1.w, s2))));
                s2 = fmaf(x2.x, x2.x, fmaf(x2.y, x2.y, fmaf(x2.z, x2.z, fmaf(x2.w, x2.w, s2))));
                s2 = fmaf(x3.x, x3.x, fmaf(x3.y, x3.y, fmaf(x3.z, x3.z, fmaf(x3.w, x3.w, s2))));

                float d[8];
#pragma unroll
                for (int hh = 0; hh < 8; ++hh) {
                    float a = x0.x * wbf[0][hh];
                    a = fmaf(x0.y, wbf[1][hh], a);
                    a = fmaf(x0.z, wbf[2][hh], a);
                    a = fmaf(x0.w, wbf[3][hh], a);
                    a = fmaf(x1.x, wbf[4][hh], a);
                    a = fmaf(x1.y, wbf[5][hh], a);
                    a = fmaf(x1.z, wbf[6][hh], a);
                    a = fmaf(x1.w, wbf[7][hh], a);
                    a = fmaf(x2.x, wbf[8][hh], a);
                    a = fmaf(x2.y, wbf[9][hh], a);
                    a = fmaf(x2.z, wbf[10][hh], a);
                    a = fmaf(x2.w, wbf[11][hh], a);
                    a = fmaf(x3.x, wbf[12][hh], a);
                    a = fmaf(x3.y, wbf[13][hh], a);
                    a = fmaf(x3.z, wbf[14][hh], a);
                    a = fmaf(x3.w, wbf[15][hh], a);
                    d[hh] = a;
                }
#pragma unroll
                for (int off = 1; off < 8; off <<= 1) {
                    s1 += __shfl_xor(s1, off);
                    s2 += __shfl_xor(s2, off);
#pragma unroll
                    for (int hh = 0; hh < 8; ++hh) d[hh] += __shfl_xor(d[hh], off);
                }
                const float mu = s1 * (1.f / 128.f);
                const float rstd = rsqrtf(s2 * (1.f / 128.f) - mu * mu + 1e-5f);
                const float dg = sel8(d, g);
                bias[(row0 + (size_t)t * TROWS + rl) * 8 + g] =
                    rstd * (dg - mu * c1s) + c0s;
            }
            float* tmp = cur; cur = nxt; nxt = tmp;
        }
    }
#undef PREFETCH
}

// ---------------------------------------------------------------------------
// K2b: flash attention, software-pipelined (round-4 body, wrapped in reps).
// ---------------------------------------------------------------------------
__global__ __launch_bounds__(256) void k_attn3(
    const float* __restrict__ bias,
    const float* __restrict__ q, const float* __restrict__ k,
    const float* __restrict__ v, const float* __restrict__ g,
    float* __restrict__ res, int reps)
{
    __shared__ float mrg[4][64][6];
    const int tid = threadIdx.x;
    const int wave = tid >> 6, lane = tid & 63;
    const int bi = blockIdx.x;
    const int b = bi / NN;
    const int h = lane >> 3;

    const float4 q4 = ((const float4*)q)[(size_t)bi * 64 + lane];
    const float* brow = bias + (size_t)bi * NN * 8;
    const size_t kb = (size_t)b * NN * 64;   // float4 base of K/V for batch b

    float m = -3e38f, s = 0.f;
    float4 acc = make_float4(0.f, 0.f, 0.f, 0.f);

    for (int rep = 0; rep < reps; ++rep) {
        m = -3e38f; s = 0.f;
        acc = make_float4(0.f, 0.f, 0.f, 0.f);

        float4 kc[4], vc[4];
        float bc[4];
#pragma unroll
        for (int u = 0; u < 4; ++u) {
            const int j = wave * 4 + u;
            kc[u] = ((const float4*)k)[kb + (size_t)j * 64 + lane];
            vc[u] = ((const float4*)v)[kb + (size_t)j * 64 + lane];
            bc[u] = brow[j * 8 + h];
        }

        for (int t = 0; t < NN / 16; ++t) {
            float4 kn[4], vn[4];
            float bn[4];
            if (t < NN / 16 - 1) {
#pragma unroll
                for (int u = 0; u < 4; ++u) {
                    const int j = (t + 1) * 16 + wave * 4 + u;
                    kn[u] = ((const float4*)k)[kb + (size_t)j * 64 + lane];
                    vn[u] = ((const float4*)v)[kb + (size_t)j * 64 + lane];
                    bn[u] = brow[j * 8 + h];
                }
            }

            float l[4];
#pragma unroll
            for (int u = 0; u < 4; ++u) {
                float d = fmaf(q4.x, kc[u].x, fmaf(q4.y, kc[u].y,
                          fmaf(q4.z, kc[u].z, q4.w * kc[u].w)));
                d += __shfl_xor(d, 1);
                d += __shfl_xor(d, 2);
                d += __shfl_xor(d, 4);
                l[u] = d + bc[u];
            }
            const float lm = fmaxf(fmaxf(l[0], l[1]), fmaxf(l[2], l[3]));
            const float mn = fmaxf(m, lm);
            const float sc = __expf(m - mn);
            float p[4];
#pragma unroll
            for (int u = 0; u < 4; ++u) p[u] = __expf(l[u] - mn);
            s = fmaf(s, sc, (p[0] + p[1]) + (p[2] + p[3]));
            m = mn;
            acc.x = fmaf(p[3], vc[3].x, fmaf(p[2], vc[2].x,
                    fmaf(p[1], vc[1].x, fmaf(p[0], vc[0].x, acc.x * sc))));
            acc.y = fmaf(p[3], vc[3].y, fmaf(p[2], vc[2].y,
                    fmaf(p[1], vc[1].y, fmaf(p[0], vc[0].y, acc.y * sc))));
            acc.z = fmaf(p[3], vc[3].z, fmaf(p[2], vc[2].z,
                    fmaf(p[1], vc[1].z, fmaf(p[0], vc[0].z, acc.z * sc))));
            acc.w = fmaf(p[3], vc[3].w, fmaf(p[2], vc[2].w,
                    fmaf(p[1], vc[1].w, fmaf(p[0], vc[0].w, acc.w * sc))));

            if (t < NN / 16 - 1) {
#pragma unroll
                for (int u = 0; u < 4; ++u) {
                    kc[u] = kn[u];
                    vc[u] = vn[u];
                    bc[u] = bn[u];
                }
            }
        }
    }

    mrg[wave][lane][0] = m;
    mrg[wave][lane][1] = s;
    mrg[wave][lane][2] = acc.x;
    mrg[wave][lane][3] = acc.y;
    mrg[wave][lane][4] = acc.z;
    mrg[wave][lane][5] = acc.w;
    __syncthreads();
    if (wave == 0) {
        float M = mrg[0][lane][0];
#pragma unroll
        for (int w2 = 1; w2 < 4; ++w2) M = fmaxf(M, mrg[w2][lane][0]);
        float S = 0.f;
        float4 A = make_float4(0.f, 0.f, 0.f, 0.f);
#pragma unroll
        for (int w2 = 0; w2 < 4; ++w2) {
            const float sc = __expf(mrg[w2][lane][0] - M);
            S = fmaf(mrg[w2][lane][1], sc, S);
            A.x = fmaf(mrg[w2][lane][2], sc, A.x);
            A.y = fmaf(mrg[w2][lane][3], sc, A.y);
            A.z = fmaf(mrg[w2][lane][4], sc, A.z);
            A.w = fmaf(mrg[w2][lane][5], sc, A.w);
        }
        const float4 g4 = ((const float4*)g)[(size_t)bi * 64 + lane];
        const float inv = 1.f / S;
        float4 r;
        r.x = A.x * inv * g4.x;
        r.y = A.y * inv * g4.y;
        r.z = A.z * inv * g4.z;
        r.w = A.w * inv * g4.w;
        ((float4*)res)[(size_t)bi * 64 + lane] = r;
    }
}

// ---------------------------------------------------------------------------
// K3: out = res @ Wo + bo.  8 rows per block.
// ---------------------------------------------------------------------------
__global__ __launch_bounds__(256) void k_outproj(
    const float* __restrict__ res, const float* __restrict__ Wo,
    const float* __restrict__ bo, float* __restrict__ out)
{
    __shared__ float xs[8][256];
    const int tid = threadIdx.x;
    const int row0 = blockIdx.x * 8;

#pragma unroll
    for (int t = tid; t < 512; t += 256)
        ((float4*)&xs[0][0])[t] = ((const float4*)(res + (size_t)row0 * 256))[t];
    __syncthreads();

    float a[8] = {};
    for (int e4 = 0; e4 < 64; ++e4) {
        const int e = e4 * 4;
        float w_[4];
#pragma unroll
        for (int t = 0; t < 4; ++t) w_[t] = Wo[(e + t) * 256 + tid];
#pragma unroll
        for (int r = 0; r < 8; ++r) {
            float4 xr = *(const float4*)&xs[r][e];
            a[r] = fmaf(xr.x, w_[0], fmaf(xr.y, w_[1], fmaf(xr.z, w_[2], fmaf(xr.w, w_[3], a[r]))));
        }
    }
    const float bov = bo[tid];
#pragma unroll
    for (int r = 0; r < 8; ++r)
        out[(size_t)(row0 + r) * 256 + tid] = a[r] + bov;
}

// ---------------------------------------------------------------------------
extern "C" void kernel_launch(void* const* d_in, const int* in_sizes, int n_in,
                              void* d_out, int out_size, void* d_ws, size_t ws_size,
                              hipStream_t stream) {
    const float* node = (const float*)d_in[0];
    const float* edge = (const float*)d_in[1];
    const float* lnnw = (const float*)d_in[2];
    const float* lnnb = (const float*)d_in[3];
    const float* lnew = (const float*)d_in[4];
    const float* lneb = (const float*)d_in[5];
    const float* Wq   = (const float*)d_in[6];
    const float* Wk   = (const float*)d_in[7];
    const float* Wv   = (const float*)d_in[8];
    const float* Wb   = (const float*)d_in[9];
    const float* Wg   = (const float*)d_in[10];
    const float* bg   = (const float*)d_in[11];
    const float* Wo   = (const float*)d_in[12];
    const float* bo   = (const float*)d_in[13];
    float* out = (float*)d_out;

    float* ws = (float*)d_ws;
    const size_t NT = (size_t)BN * 256;
    float* q    = ws;
    float* k    = ws + NT;
    float* v    = ws + 2 * NT;
    float* g    = ws + 3 * NT;
    float* res  = ws + 4 * NT;
    float* bias = ws + 5 * NT;            // 9.44M floats = 37.75 MB

    k_lnproj<<<BN / 8, 256, 0, stream>>>(node, lnnw, lnnb, Wq, Wk, Wv, Wg, bg, q, k, v, g);
    k_bias<<<256, 256, 0, stream>>>(edge, lnew, lneb, Wb, bias, 4);
    k_attn3<<<BN, 256, 0, stream>>>(bias, q, k, v, g, res, 4);
    k_outproj<<<BN / 8, 256, 0, stream>>>(res, Wo, bo, out);
}

// Round 6
// 353.823 us; speedup vs baseline: 2.9803x; 2.9803x over previous
//
#include <hip/hip_runtime.h>
#include <hip/hip_bf16.h>
#include <math.h>

// Problem dims (fixed by reference)
#define BN 1536          // B*N = 2*768
#define NN 768
#define SCALE 0.17677669529663687f  // 1/sqrt(32)
#define NROWS (BN * NN)  // total edge rows = 1179648

// select a[idx] from a compile-time-unrolled register array (idx per-lane runtime)
__device__ __forceinline__ float sel8(const float* a, int idx) {
    float r = a[0];
#pragma unroll
    for (int t = 1; t < 8; ++t) r = (idx == t) ? a[t] : r;
    return r;
}

// ---- DPP reduction helpers (VALU pipe; no LDS traffic) ---------------------
// sum over each 16-lane DPP row; afterwards ALL 16 lanes hold the total
__device__ __forceinline__ float dpp_add16(float x) {
    int t;
    t = __builtin_amdgcn_update_dpp(0, __float_as_int(x), 0x128, 0xF, 0xF, true); // row_ror:8
    x += __int_as_float(t);
    t = __builtin_amdgcn_update_dpp(0, __float_as_int(x), 0x124, 0xF, 0xF, true); // row_ror:4
    x += __int_as_float(t);
    t = __builtin_amdgcn_update_dpp(0, __float_as_int(x), 0x122, 0xF, 0xF, true); // row_ror:2
    x += __int_as_float(t);
    t = __builtin_amdgcn_update_dpp(0, __float_as_int(x), 0x121, 0xF, 0xF, true); // row_ror:1
    x += __int_as_float(t);
    return x;
}
__device__ __forceinline__ float dpp_xor1_add(float x) {   // x += lane^1 (quad_perm 1,0,3,2)
    int t = __builtin_amdgcn_update_dpp(0, __float_as_int(x), 0xB1, 0xF, 0xF, true);
    return x + __int_as_float(t);
}
__device__ __forceinline__ float dpp_xor2_add(float x) {   // x += lane^2 (quad_perm 2,3,0,1)
    int t = __builtin_amdgcn_update_dpp(0, __float_as_int(x), 0x4E, 0xF, 0xF, true);
    return x + __int_as_float(t);
}

// ---------------------------------------------------------------------------
// K1: x = LN(node); q = SCALE*(x@Wq); k = x@Wk; v = x@Wv; g = sigmoid(x@Wg+bg)
// ---------------------------------------------------------------------------
__global__ __launch_bounds__(256) void k_lnproj(
    const float* __restrict__ node, const float* __restrict__ lnw,
    const float* __restrict__ lnb, const float* __restrict__ Wq,
    const float* __restrict__ Wk, const float* __restrict__ Wv,
    const float* __restrict__ Wg, const float* __restrict__ bg,
    float* __restrict__ q, float* __restrict__ k,
    float* __restrict__ v, float* __restrict__ g)
{
    __shared__ float xs[8][256];
    const int tid = threadIdx.x;
    const int wave = tid >> 6, lane = tid & 63;
    const int row0 = blockIdx.x * 8;

#pragma unroll
    for (int rr = 0; rr < 2; ++rr) {
        const int r = wave * 2 + rr;
        float4 xv = ((const float4*)node)[(size_t)(row0 + r) * 64 + lane];
        float s1 = xv.x + xv.y + xv.z + xv.w;
        float s2 = fmaf(xv.x, xv.x, fmaf(xv.y, xv.y, fmaf(xv.z, xv.z, xv.w * xv.w)));
#pragma unroll
        for (int off = 32; off > 0; off >>= 1) {
            s1 += __shfl_xor(s1, off);
            s2 += __shfl_xor(s2, off);
        }
        const float mu = s1 * (1.f / 256.f);
        const float rstd = rsqrtf(s2 * (1.f / 256.f) - mu * mu + 1e-5f);
        float4 w4 = ((const float4*)lnw)[lane];
        float4 b4 = ((const float4*)lnb)[lane];
        xs[r][lane * 4 + 0] = (xv.x - mu) * rstd * w4.x + b4.x;
        xs[r][lane * 4 + 1] = (xv.y - mu) * rstd * w4.y + b4.y;
        xs[r][lane * 4 + 2] = (xv.z - mu) * rstd * w4.z + b4.z;
        xs[r][lane * 4 + 3] = (xv.w - mu) * rstd * w4.w + b4.w;
    }
    __syncthreads();

    float aq[8] = {}, ak[8] = {}, av[8] = {}, ag[8] = {};
    for (int e4 = 0; e4 < 64; ++e4) {
        const int e = e4 * 4;
        float wq_[4], wk_[4], wv_[4], wg_[4];
#pragma unroll
        for (int t = 0; t < 4; ++t) {
            wq_[t] = Wq[(e + t) * 256 + tid];
            wk_[t] = Wk[(e + t) * 256 + tid];
            wv_[t] = Wv[(e + t) * 256 + tid];
            wg_[t] = Wg[(e + t) * 256 + tid];
        }
#pragma unroll
        for (int r = 0; r < 8; ++r) {
            float4 xr = *(const float4*)&xs[r][e];
            aq[r] = fmaf(xr.x, wq_[0], fmaf(xr.y, wq_[1], fmaf(xr.z, wq_[2], fmaf(xr.w, wq_[3], aq[r]))));
            ak[r] = fmaf(xr.x, wk_[0], fmaf(xr.y, wk_[1], fmaf(xr.z, wk_[2], fmaf(xr.w, wk_[3], ak[r]))));
            av[r] = fmaf(xr.x, wv_[0], fmaf(xr.y, wv_[1], fmaf(xr.z, wv_[2], fmaf(xr.w, wv_[3], av[r]))));
            ag[r] = fmaf(xr.x, wg_[0], fmaf(xr.y, wg_[1], fmaf(xr.z, wg_[2], fmaf(xr.w, wg_[3], ag[r]))));
        }
    }
    const float bgv = bg[tid];
#pragma unroll
    for (int r = 0; r < 8; ++r) {
        const size_t o = (size_t)(row0 + r) * 256 + tid;
        q[o] = aq[r] * SCALE;
        k[o] = ak[r];
        v[o] = av[r];
        g[o] = 1.f / (1.f + __expf(-(ag[r] + bgv)));
    }
}

// ---------------------------------------------------------------------------
// K2a v3: bias[r][h] = LN(edge_row r) @ Wb  — zero-LDS, DPP-reduce.
// 16 lanes/row (gl), 4 rows per wave pass (rg = lane>>4). Lane owns channels
// [4gl..4gl+3] and [64+4gl..64+4gl+3] (two contiguous float4 loads per row).
// Folded LN: bias_h = rstd*(d_h - mu*c1_h) + c0_h. All reductions via DPP
// row_ror (VALU pipe). Double-buffered register prefetch, no barriers.
// 1024 blocks x 4 waves = 4096 waves x 288 rows.
// ---------------------------------------------------------------------------
__global__ __launch_bounds__(256, 4) void k_bias(
    const float* __restrict__ edge, const float* __restrict__ lnw,
    const float* __restrict__ lnb, const float* __restrict__ Wb,
    float* __restrict__ bias)
{
    const int tid = threadIdx.x;
    const int wv = tid >> 6, lane = tid & 63;
    const int gl = lane & 15;
    const int rg = lane >> 4;

    // folded weights for this lane's 8 channels
    float wbf[8][8];
    float c1s[8], c0s[8];
#pragma unroll
    for (int hh = 0; hh < 8; ++hh) { c1s[hh] = 0.f; c0s[hh] = 0.f; }
#pragma unroll
    for (int t = 0; t < 8; ++t) {
        const int c = (t < 4) ? (gl * 4 + t) : (64 + gl * 4 + (t - 4));
        const float w = lnw[c], bb = lnb[c];
        const float4 wa = ((const float4*)Wb)[c * 2];
        const float4 wc = ((const float4*)Wb)[c * 2 + 1];
        wbf[t][0] = w * wa.x; wbf[t][1] = w * wa.y;
        wbf[t][2] = w * wa.z; wbf[t][3] = w * wa.w;
        wbf[t][4] = w * wc.x; wbf[t][5] = w * wc.y;
        wbf[t][6] = w * wc.z; wbf[t][7] = w * wc.w;
        c0s[0] = fmaf(bb, wa.x, c0s[0]); c0s[1] = fmaf(bb, wa.y, c0s[1]);
        c0s[2] = fmaf(bb, wa.z, c0s[2]); c0s[3] = fmaf(bb, wa.w, c0s[3]);
        c0s[4] = fmaf(bb, wc.x, c0s[4]); c0s[5] = fmaf(bb, wc.y, c0s[5]);
        c0s[6] = fmaf(bb, wc.z, c0s[6]); c0s[7] = fmaf(bb, wc.w, c0s[7]);
#pragma unroll
        for (int hh = 0; hh < 8; ++hh) c1s[hh] += wbf[t][hh];
    }
#pragma unroll
    for (int hh = 0; hh < 8; ++hh) {
        c1s[hh] = dpp_add16(c1s[hh]);
        c0s[hh] = dpp_add16(c0s[hh]);
    }
    const float c1l = sel8(c1s, gl & 7);
    const float c0l = sel8(c0s, gl & 7);

    const int w = blockIdx.x * 4 + wv;     // 0..4095
    const int row0 = w * 288;
    const float4* ep = (const float4*)edge;

    float4 a0, a1, b0, b1;
    {
        const size_t r = (size_t)(row0 + rg);
        a0 = ep[r * 32 + gl];
        a1 = ep[r * 32 + 16 + gl];
    }

    for (int it = 0; it < 72; ++it) {
        if (it < 71) {
            const size_t r = (size_t)(row0 + (it + 1) * 4 + rg);
            b0 = ep[r * 32 + gl];
            b1 = ep[r * 32 + 16 + gl];
        }

        float s1 = ((a0.x + a0.y) + (a0.z + a0.w)) + ((a1.x + a1.y) + (a1.z + a1.w));
        float s2 = fmaf(a0.x, a0.x, fmaf(a0.y, a0.y, fmaf(a0.z, a0.z, a0.w * a0.w)));
        s2 = fmaf(a1.x, a1.x, fmaf(a1.y, a1.y, fmaf(a1.z, a1.z, fmaf(a1.w, a1.w, s2))));

        float d[8];
#pragma unroll
        for (int hh = 0; hh < 8; ++hh) {
            float a = a0.x * wbf[0][hh];
            a = fmaf(a0.y, wbf[1][hh], a);
            a = fmaf(a0.z, wbf[2][hh], a);
            a = fmaf(a0.w, wbf[3][hh], a);
            a = fmaf(a1.x, wbf[4][hh], a);
            a = fmaf(a1.y, wbf[5][hh], a);
            a = fmaf(a1.z, wbf[6][hh], a);
            a = fmaf(a1.w, wbf[7][hh], a);
            d[hh] = a;
        }

        s1 = dpp_add16(s1);
        s2 = dpp_add16(s2);
#pragma unroll
        for (int hh = 0; hh < 8; ++hh) d[hh] = dpp_add16(d[hh]);

        const float mu = s1 * (1.f / 128.f);
        const float rstd = rsqrtf(s2 * (1.f / 128.f) - mu * mu + 1e-5f);
        if (gl < 8) {
            const float dh = sel8(d, gl);
            bias[(size_t)(row0 + it * 4 + rg) * 8 + gl] =
                rstd * (dh - mu * c1l) + c0l;
        }

        a0 = b0; a1 = b1;
    }
}

// ---------------------------------------------------------------------------
// K2b v3: flash attention, one wave per q-row, 4 rows per block (L1 K/V reuse).
// lane = (h = lane>>3, dq = lane&7) owns head h dims dq*4..dq*4+3.
// Octet reduce: 2 quad-perm DPP adds + one shfl_xor(4).
// K/V 1-deep prefetch (L2-resident); bias 2-deep (L3 latency).
// No LDS, no barriers, no cross-wave merge.
// ---------------------------------------------------------------------------
__global__ __launch_bounds__(256) void k_attn4(
    const float* __restrict__ bias,
    const float* __restrict__ q, const float* __restrict__ k,
    const float* __restrict__ v, const float* __restrict__ g,
    float* __restrict__ res)
{
    const int tid = threadIdx.x;
    const int wv = tid >> 6, lane = tid & 63;
    const int bi = blockIdx.x * 4 + wv;
    const int b = bi / NN;
    const int h = lane >> 3;

    const float4 q4 = ((const float4*)q)[(size_t)bi * 64 + lane];
    const float* brow = bias + (size_t)bi * NN * 8;
    const size_t kb = (size_t)b * NN * 64;

    float m = -3e38f, s = 0.f;
    float4 acc = make_float4(0.f, 0.f, 0.f, 0.f);

    float4 kc[4], vc[4];
    float bc[4], bn1[4];
#pragma unroll
    for (int u = 0; u < 4; ++u) {
        kc[u] = ((const float4*)k)[kb + (size_t)u * 64 + lane];
        vc[u] = ((const float4*)v)[kb + (size_t)u * 64 + lane];
        bc[u]  = brow[u * 8 + h];
        bn1[u] = brow[(4 + u) * 8 + h];
    }

    for (int t = 0; t < NN / 4; ++t) {
        float4 kn[4], vn[4];
        float bn2[4];
        if (t + 2 < NN / 4) {
#pragma unroll
            for (int u = 0; u < 4; ++u)
                bn2[u] = brow[((t + 2) * 4 + u) * 8 + h];
        }
        if (t + 1 < NN / 4) {
#pragma unroll
            for (int u = 0; u < 4; ++u) {
                kn[u] = ((const float4*)k)[kb + (size_t)((t + 1) * 4 + u) * 64 + lane];
                vn[u] = ((const float4*)v)[kb + (size_t)((t + 1) * 4 + u) * 64 + lane];
            }
        }

        float l[4];
#pragma unroll
        for (int u = 0; u < 4; ++u) {
            float d = fmaf(q4.x, kc[u].x, fmaf(q4.y, kc[u].y,
                      fmaf(q4.z, kc[u].z, q4.w * kc[u].w)));
            d = dpp_xor1_add(d);
            d = dpp_xor2_add(d);
            d += __shfl_xor(d, 4);
            l[u] = d + bc[u];
        }
        const float lm = fmaxf(fmaxf(l[0], l[1]), fmaxf(l[2], l[3]));
        const float mn = fmaxf(m, lm);
        const float sc = __expf(m - mn);
        float p[4];
#pragma unroll
        for (int u = 0; u < 4; ++u) p[u] = __expf(l[u] - mn);
        s = fmaf(s, sc, (p[0] + p[1]) + (p[2] + p[3]));
        m = mn;
        acc.x = fmaf(p[3], vc[3].x, fmaf(p[2], vc[2].x,
                fmaf(p[1], vc[1].x, fmaf(p[0], vc[0].x, acc.x * sc))));
        acc.y = fmaf(p[3], vc[3].y, fmaf(p[2], vc[2].y,
                fmaf(p[1], vc[1].y, fmaf(p[0], vc[0].y, acc.y * sc))));
        acc.z = fmaf(p[3], vc[3].z, fmaf(p[2], vc[2].z,
                fmaf(p[1], vc[1].z, fmaf(p[0], vc[0].z, acc.z * sc))));
        acc.w = fmaf(p[3], vc[3].w, fmaf(p[2], vc[2].w,
                fmaf(p[1], vc[1].w, fmaf(p[0], vc[0].w, acc.w * sc))));

        if (t + 1 < NN / 4) {
#pragma unroll
            for (int u = 0; u < 4; ++u) { kc[u] = kn[u]; vc[u] = vn[u]; }
        }
#pragma unroll
        for (int u = 0; u < 4; ++u) bc[u] = bn1[u];
        if (t + 2 < NN / 4) {
#pragma unroll
            for (int u = 0; u < 4; ++u) bn1[u] = bn2[u];
        }
    }

    const float4 g4 = ((const float4*)g)[(size_t)bi * 64 + lane];
    const float inv = 1.f / s;
    float4 r;
    r.x = acc.x * inv * g4.x;
    r.y = acc.y * inv * g4.y;
    r.z = acc.z * inv * g4.z;
    r.w = acc.w * inv * g4.w;
    ((float4*)res)[(size_t)bi * 64 + lane] = r;
}

// ---------------------------------------------------------------------------
// K3: out = res @ Wo + bo.  8 rows per block.
// ---------------------------------------------------------------------------
__global__ __launch_bounds__(256) void k_outproj(
    const float* __restrict__ res, const float* __restrict__ Wo,
    const float* __restrict__ bo, float* __restrict__ out)
{
    __shared__ float xs[8][256];
    const int tid = threadIdx.x;
    const int row0 = blockIdx.x * 8;

#pragma unroll
    for (int t = tid; t < 512; t += 256)
        ((float4*)&xs[0][0])[t] = ((const float4*)(res + (size_t)row0 * 256))[t];
    __syncthreads();

    float a[8] = {};
    for (int e4 = 0; e4 < 64; ++e4) {
        const int e = e4 * 4;
        float w_[4];
#pragma unroll
        for (int t = 0; t < 4; ++t) w_[t] = Wo[(e + t) * 256 + tid];
#pragma unroll
        for (int r = 0; r < 8; ++r) {
            float4 xr = *(const float4*)&xs[r][e];
            a[r] = fmaf(xr.x, w_[0], fmaf(xr.y, w_[1], fmaf(xr.z, w_[2], fmaf(xr.w, w_[3], a[r]))));
        }
    }
    const float bov = bo[tid];
#pragma unroll
    for (int r = 0; r < 8; ++r)
        out[(size_t)(row0 + r) * 256 + tid] = a[r] + bov;
}

// ---------------------------------------------------------------------------
extern "C" void kernel_launch(void* const* d_in, const int* in_sizes, int n_in,
                              void* d_out, int out_size, void* d_ws, size_t ws_size,
                              hipStream_t stream) {
    const float* node = (const float*)d_in[0];
    const float* edge = (const float*)d_in[1];
    const float* lnnw = (const float*)d_in[2];
    const float* lnnb = (const float*)d_in[3];
    const float* lnew = (const float*)d_in[4];
    const float* lneb = (const float*)d_in[5];
    const float* Wq   = (const float*)d_in[6];
    const float* Wk   = (const float*)d_in[7];
    const float* Wv   = (const float*)d_in[8];
    const float* Wb   = (const float*)d_in[9];
    const float* Wg   = (const float*)d_in[10];
    const float* bg   = (const float*)d_in[11];
    const float* Wo   = (const float*)d_in[12];
    const float* bo   = (const float*)d_in[13];
    float* out = (float*)d_out;

    float* ws = (float*)d_ws;
    const size_t NT = (size_t)BN * 256;
    float* q    = ws;
    float* k    = ws + NT;
    float* v    = ws + 2 * NT;
    float* g    = ws + 3 * NT;
    float* res  = ws + 4 * NT;
    float* bias = ws + 5 * NT;            // 9.44M floats = 37.75 MB

    k_lnproj<<<BN / 8, 256, 0, stream>>>(node, lnnw, lnnb, Wq, Wk, Wv, Wg, bg, q, k, v, g);
    k_bias<<<1024, 256, 0, stream>>>(edge, lnew, lneb, Wb, bias);
    k_attn4<<<BN / 4, 256, 0, stream>>>(bias, q, k, v, g, res);
    k_outproj<<<BN / 8, 256, 0, stream>>>(res, Wo, bo, out);
}